// Round 3
// baseline (83.960 us; speedup 1.0000x reference)
//
#include <hip/hip_runtime.h>

#define NN 2048
#define KK 8
#define BB 32
#define TT 20

__global__ __launch_bounds__(1024) void osci_kernel(
    const float* __restrict__ coupling,   // [B,N,K]
    const float* __restrict__ phase0,     // [B,N]
    const float* __restrict__ omega,      // [B,N]
    const int*   __restrict__ conn,       // [N,K]
    float*       __restrict__ out)        // [T+1,B,N]
{
    const int b   = blockIdx.x;
    const int tid = threadIdx.x;
    const int i0  = tid * 2;              // thread owns oscillators i0, i0+1

    // double-buffered phase state: one barrier per step
    __shared__ float ph_buf[2][NN];

    int   cidx[2][KK];
    float w[2][KK];
    float om[2];
    float ph[2];

    // ---- coalesced setup loads (pair mapping => wide vectors) ----
    {
        const float2 p  = ((const float2*)(phase0 + (size_t)b * NN))[tid];
        const float2 o  = ((const float2*)(omega  + (size_t)b * NN))[tid];
        ph[0] = p.x; ph[1] = p.y;
        om[0] = o.x; om[1] = o.y;
        ((float2*)(out + (size_t)b * NN))[tid] = p;        // out[0,b,:]
        *(float2*)&ph_buf[0][i0] = p;

        #pragma unroll
        for (int t = 0; t < 2; ++t) {
            const int i = i0 + t;
            const int4   ja = ((const int4*)(conn + (size_t)i * KK))[0];
            const int4   jb = ((const int4*)(conn + (size_t)i * KK))[1];
            const float4 va = ((const float4*)(coupling + ((size_t)b * NN + i) * KK))[0];
            const float4 vb = ((const float4*)(coupling + ((size_t)b * NN + i) * KK))[1];
            int   jj[KK] = {ja.x, ja.y, ja.z, ja.w, jb.x, jb.y, jb.z, jb.w};
            float vv[KK] = {va.x, va.y, va.z, va.w, vb.x, vb.y, vb.z, vb.w};

            // last-wins scatter dedup: entry k vanishes if any k2>k hits same
            // column; n = count of surviving nonzero dense-row entries
            int cnt = 0;
            #pragma unroll
            for (int k = 0; k < KK; ++k) {
                bool over = false;
                #pragma unroll
                for (int k2 = k + 1; k2 < KK; ++k2) over = over || (jj[k2] == jj[k]);
                if (over) vv[k] = 0.0f;
                if (vv[k] != 0.0f) ++cnt;
            }
            const float nf = (float)cnt;      // cnt >= 1 (last write survives)
            #pragma unroll
            for (int k = 0; k < KK; ++k) {
                cidx[t][k] = jj[k];
                w[t][k]    = vv[k] / nf;      // fold 1/n into weights (setup-only)
            }
        }
    }
    __syncthreads();

    for (int step = 0; step < TT; ++step) {
        const int cur = step & 1;
        const int nxt = cur ^ 1;

        const float ri0 = ph[0], ri1 = ph[1];
        float acc0 = 0.0f, acc1 = 0.0f;
        // Cs*c - Cc*s == sum_k w_k * sin(phi_jk - phi_i); both oscillators
        // interleaved for ILP on the LDS gathers + v_sin chain
        #pragma unroll
        for (int k = 0; k < KK; ++k) {
            const float pj0 = ph_buf[cur][cidx[0][k]];
            const float pj1 = ph_buf[cur][cidx[1][k]];
            acc0 += w[0][k] * __sinf(pj0 - ri0);
            acc1 += w[1][k] * __sinf(pj1 - ri1);
        }
        const float pn0 = ri0 + acc0 + om[0];   // eps=1, ANNEAL=0
        const float pn1 = ri1 + acc1 + om[1];
        ph[0] = pn0; ph[1] = pn1;

        *(float2*)&ph_buf[nxt][i0] = make_float2(pn0, pn1);           // ds_write_b64
        *(float2*)&out[((size_t)(step + 1) * BB + b) * NN + i0] = make_float2(pn0, pn1);

        __syncthreads();   // writes to nxt visible before next step's gathers
    }
}

extern "C" void kernel_launch(void* const* d_in, const int* in_sizes, int n_in,
                              void* d_out, int out_size, void* d_ws, size_t ws_size,
                              hipStream_t stream) {
    const float* coupling = (const float*)d_in[0];   // [B,N,K]
    const float* phase0   = (const float*)d_in[1];   // [B,N]
    const float* omega    = (const float*)d_in[2];   // [B,N]
    const int*   conn     = (const int*)d_in[3];     // [N,K]
    float* out = (float*)d_out;                      // [T+1,B,N]

    osci_kernel<<<BB, 1024, 0, stream>>>(coupling, phase0, omega, conn, out);
}